// Round 1
// baseline (706.901 us; speedup 1.0000x reference)
//
#include <hip/hip_runtime.h>

#define DD 64

// ---------------- degree count ----------------
__global__ void k_deg(const int* __restrict__ src, const int* __restrict__ dst,
                      int* __restrict__ cout_, int* __restrict__ cin_, int E) {
    int e = blockIdx.x * blockDim.x + threadIdx.x;
    if (e < E) {
        atomicAdd(&cout_[src[e]], 1);
        atomicAdd(&cin_[dst[e]], 1);
    }
}

__global__ void k_inv(const int* __restrict__ cout_, const int* __restrict__ cin_,
                      float* __restrict__ oinv, float* __restrict__ iinv, int n) {
    int i = blockIdx.x * blockDim.x + threadIdx.x;
    if (i < n) {
        oinv[i] = rsqrtf((float)max(cout_[i], 1));
        iinv[i] = rsqrtf((float)max(cin_[i], 1));
    }
}

// ---------------- edge scatter-sum: y[dst[e]][d] += x[src[e]][d] * scale ----------------
// MODE 0: scale = oinv[src[e]]           (layer 0 input scaling)
// MODE 1: scale = 1                      (layer 1; scaling pre-applied to x)
// MODE 2: scale = e_feat even ? 2 : 1    (final message coef)
template <int MODE>
__global__ __launch_bounds__(256) void k_scatter(const float* __restrict__ x,
                                                 const int* __restrict__ src,
                                                 const int* __restrict__ dst,
                                                 const float* __restrict__ sscale,
                                                 const int* __restrict__ efeat,
                                                 float* __restrict__ y, int E) {
    int t = blockIdx.x * 256 + threadIdx.x;
    int e = t >> 6;                 // 4 edges per block, one wave-lane per feature
    if (e >= E) return;
    int d = t & 63;
    int s = src[e];
    float v = x[(size_t)s * DD + d];
    if (MODE == 0) v *= sscale[s];
    if (MODE == 2) v *= (efeat[e] & 1) ? 1.0f : 2.0f;
    atomicAdd(&y[(size_t)dst[e] * DD + d], v);
}

// ---------------- elementwise: h *= oinv[row] * iinv[row] ----------------
__global__ void k_scale(float* __restrict__ h, const float* __restrict__ oinv,
                        const float* __restrict__ iinv, int n) {
    int i = blockIdx.x * blockDim.x + threadIdx.x;
    if (i < n * DD) {
        int r = i >> 6;
        h[i] *= oinv[r] * iinv[r];
    }
}

// ---------------- h1 = (agg * iinv[row]) @ W + b ----------------
__global__ __launch_bounds__(256) void k_gemm(const float* __restrict__ agg,
                                              const float* __restrict__ iinv,
                                              const float* __restrict__ W,
                                              const float* __restrict__ b,
                                              float* __restrict__ h1, int n) {
    __shared__ float Wl[64 * 64];     // 16 KB
    __shared__ float rows[32][64];    // 8 KB
    int tid = threadIdx.x;
    for (int i = tid; i < 64 * 64; i += 256) Wl[i] = W[i];
    int r0 = blockIdx.x * 32;
    for (int i = tid; i < 32 * 64; i += 256) {
        int r = i >> 6;
        int gr = r0 + r;
        float v = 0.0f;
        if (gr < n) v = agg[(size_t)gr * 64 + (i & 63)] * iinv[gr];
        rows[r][i & 63] = v;
    }
    __syncthreads();
    int col = tid & 63;
    int rg = tid >> 6;               // 0..3, each handles 8 rows
    float bias = b[col];
    for (int rr = 0; rr < 8; ++rr) {
        int r = rg * 8 + rr;
        int gr = r0 + r;
        if (gr >= n) break;
        float acc = bias;
#pragma unroll
        for (int k = 0; k < 64; ++k) acc += rows[r][k] * Wl[k * 64 + col];
        h1[(size_t)gr * 64 + col] = acc;
    }
}

extern "C" void kernel_launch(void* const* d_in, const int* in_sizes, int n_in,
                              void* d_out, int out_size, void* d_ws, size_t ws_size,
                              hipStream_t stream) {
    const float* x   = (const float*)d_in[0];   // [N, 64]
    const float* W   = (const float*)d_in[1];   // [64, 64]
    const float* b   = (const float*)d_in[2];   // [64]
    const int*   src = (const int*)d_in[3];     // [E]
    const int*   dst = (const int*)d_in[4];     // [E]
    const int*   ef  = (const int*)d_in[5];     // [E]
    float* out = (float*)d_out;

    const int n = in_sizes[0] / DD;
    const int E = in_sizes[3];

    // workspace layout (256B-aligned chunks)
    char* ws = (char*)d_ws;
    size_t np = ((size_t)n + 255) & ~(size_t)255;
    int*   cout_ = (int*)ws;   ws += np * 4;
    int*   cin_  = (int*)ws;   ws += np * 4;
    float* oinv  = (float*)ws; ws += np * 4;
    float* iinv  = (float*)ws; ws += np * 4;
    size_t fbytes = (size_t)n * DD * sizeof(float);
    float* h0   = (float*)ws;  ws += fbytes;
    float* agg1 = (float*)ws;  ws += fbytes;
    float* h1   = (float*)ws;  ws += fbytes;

    // zero accumulators (ws and d_out are poisoned before every timed call)
    hipMemsetAsync(cout_, 0, np * 8, stream);            // cout_ + cin_ contiguous
    hipMemsetAsync(h0,   0, fbytes, stream);
    hipMemsetAsync(agg1, 0, fbytes, stream);
    hipMemsetAsync(out,  0, (size_t)out_size * sizeof(float), stream);

    k_deg<<<(E + 255) / 256, 256, 0, stream>>>(src, dst, cout_, cin_, E);
    k_inv<<<(n + 255) / 256, 256, 0, stream>>>(cout_, cin_, oinv, iinv, n);

    int sblocks = (E + 3) / 4;   // 4 edges per 256-thread block

    // layer 0: h0 = segsum(x[src]*oinv[src], dst); then h0 *= iinv*oinv (next layer's input scale)
    k_scatter<0><<<sblocks, 256, 0, stream>>>(x, src, dst, oinv, nullptr, h0, E);
    k_scale<<<((size_t)n * DD + 255) / 256, 256, 0, stream>>>(h0, oinv, iinv, n);

    // layer 1: agg1 = segsum(h0[src], dst); h1 = (agg1*iinv) @ W + b
    k_scatter<1><<<sblocks, 256, 0, stream>>>(h0, src, dst, nullptr, nullptr, agg1, E);
    k_gemm<<<(n + 31) / 32, 256, 0, stream>>>(agg1, iinv, W, b, h1, n);

    // final: out = segsum(h1[src]*coef, dst)
    k_scatter<2><<<sblocks, 256, 0, stream>>>(h1, src, dst, nullptr, ef, out, E);
}

// Round 2
// 420.248 us; speedup vs baseline: 1.6821x; 1.6821x over previous
//
#include <hip/hip_runtime.h>

#define DD 64

// ---------------- degree histogram ----------------
__global__ void k_hist(const int* __restrict__ src, const int* __restrict__ dst,
                       int* __restrict__ cout_, int* __restrict__ cin_, int E) {
    int e = blockIdx.x * blockDim.x + threadIdx.x;
    if (e < E) {
        atomicAdd(&cout_[src[e]], 1);
        atomicAdd(&cin_[dst[e]], 1);
    }
}

__global__ void k_inv(const int* __restrict__ cout_, const int* __restrict__ cin_,
                      float* __restrict__ oinv, float* __restrict__ iinv, int n) {
    int i = blockIdx.x * blockDim.x + threadIdx.x;
    if (i < n) {
        oinv[i] = rsqrtf((float)max(cout_[i], 1));
        iinv[i] = rsqrtf((float)max(cin_[i], 1));
    }
}

// ---------------- single-block exclusive scan: cnt[0..n) -> row_start[0..n], cursor copy ----------------
__global__ __launch_bounds__(1024) void k_scan(const int* __restrict__ cnt,
                                               int* __restrict__ row_start,
                                               int* __restrict__ cursor, int n) {
    __shared__ int part[1024];
    int t = threadIdx.x;
    int C = (n + 1023) >> 10;
    int lo = t * C, hi = min(lo + C, n);
    int s = 0;
    for (int i = lo; i < hi; ++i) s += cnt[i];
    part[t] = s;
    __syncthreads();
    for (int off = 1; off < 1024; off <<= 1) {
        int v = (t >= off) ? part[t - off] : 0;
        __syncthreads();
        part[t] += v;
        __syncthreads();
    }
    int run = (t == 0) ? 0 : part[t - 1];
    for (int i = lo; i < hi; ++i) {
        row_start[i] = run;
        cursor[i] = run;
        run += cnt[i];
    }
    if (t == 1023) row_start[n] = part[1023];   // = E
}

// ---------------- CSR fill: dst-sorted (src, ef) records ----------------
__global__ void k_fill(const int* __restrict__ src, const int* __restrict__ dst,
                       const int* __restrict__ ef, int* __restrict__ cursor,
                       int2* __restrict__ edges, int E) {
    int e = blockIdx.x * blockDim.x + threadIdx.x;
    if (e < E) {
        int pos = atomicAdd(&cursor[dst[e]], 1);
        edges[pos] = make_int2(src[e], ef[e]);
    }
}

// ---------------- gather-sum: y[v] = post(v) * sum_{edges of v} scale(e) * x[src] ----------------
// MODE 0: scale = oinv[src], post = iinv[v]*oinv[v]   (layer0 + fold next layer's input scale)
// MODE 1: scale = 1,         post = iinv[v]           (layer1 aggregation)
// MODE 2: scale = ef even ? 2 : 1, post = 1           (final message pass)
template <int MODE>
__global__ __launch_bounds__(256) void k_gather(const float* __restrict__ x,
                                                const int2* __restrict__ edges,
                                                const int* __restrict__ row_start,
                                                const float* __restrict__ oinv,
                                                const float* __restrict__ iinv,
                                                float* __restrict__ y, int n) {
    int wave = (blockIdx.x * 256 + threadIdx.x) >> 6;
    if (wave >= n) return;
    int lane = threadIdx.x & 63;
    int sub = lane >> 4;        // 0..3 : edge slot
    int q = lane & 15;          // feature quad: floats [4q, 4q+4)
    int s0 = row_start[wave], s1 = row_start[wave + 1];
    float ax = 0.f, ay = 0.f, az = 0.f, aw = 0.f;
    for (int i = s0 + sub; i < s1; i += 4) {
        int2 e = edges[i];
        const float4 v = *(const float4*)(x + (size_t)e.x * DD + q * 4);
        float sc = 1.0f;
        if (MODE == 0) sc = oinv[e.x];
        if (MODE == 2) sc = (e.y & 1) ? 1.0f : 2.0f;
        ax = fmaf(v.x, sc, ax);
        ay = fmaf(v.y, sc, ay);
        az = fmaf(v.z, sc, az);
        aw = fmaf(v.w, sc, aw);
    }
    // reduce the 4 edge-slots (lanes q, q+16, q+32, q+48)
    ax += __shfl_xor(ax, 16); ay += __shfl_xor(ay, 16);
    az += __shfl_xor(az, 16); aw += __shfl_xor(aw, 16);
    ax += __shfl_xor(ax, 32); ay += __shfl_xor(ay, 32);
    az += __shfl_xor(az, 32); aw += __shfl_xor(aw, 32);
    if (sub == 0) {
        float post = 1.0f;
        if (MODE == 0) post = iinv[wave] * oinv[wave];
        if (MODE == 1) post = iinv[wave];
        float4 o = make_float4(ax * post, ay * post, az * post, aw * post);
        *(float4*)(y + (size_t)wave * DD + q * 4) = o;
    }
}

// ---------------- h1 = agg @ W + b  (in-place safe: block reads its rows before writing) ----------------
__global__ __launch_bounds__(256) void k_gemm(const float* __restrict__ agg,
                                              const float* __restrict__ W,
                                              const float* __restrict__ b,
                                              float* __restrict__ h1, int n) {
    __shared__ float Wl[64 * 64];     // 16 KB
    __shared__ float rows[32][64];    // 8 KB
    int tid = threadIdx.x;
    for (int i = tid; i < 64 * 64; i += 256) Wl[i] = W[i];
    int r0 = blockIdx.x * 32;
    for (int i = tid; i < 32 * 64; i += 256) {
        int r = i >> 6;
        int gr = r0 + r;
        rows[r][i & 63] = (gr < n) ? agg[(size_t)gr * 64 + (i & 63)] : 0.0f;
    }
    __syncthreads();
    int col = tid & 63;
    int rg = tid >> 6;               // 0..3, each handles 8 rows
    float bias = b[col];
    for (int rr = 0; rr < 8; ++rr) {
        int r = rg * 8 + rr;
        int gr = r0 + r;
        if (gr >= n) break;
        float acc = bias;
#pragma unroll
        for (int k = 0; k < 64; ++k) acc += rows[r][k] * Wl[k * 64 + col];
        h1[(size_t)gr * 64 + col] = acc;
    }
}

extern "C" void kernel_launch(void* const* d_in, const int* in_sizes, int n_in,
                              void* d_out, int out_size, void* d_ws, size_t ws_size,
                              hipStream_t stream) {
    const float* x   = (const float*)d_in[0];   // [N, 64]
    const float* W   = (const float*)d_in[1];   // [64, 64]
    const float* b   = (const float*)d_in[2];   // [64]
    const int*   src = (const int*)d_in[3];     // [E]
    const int*   dst = (const int*)d_in[4];     // [E]
    const int*   ef  = (const int*)d_in[5];     // [E]
    float* out = (float*)d_out;

    const int n = in_sizes[0] / DD;
    const int E = in_sizes[3];

    // workspace layout
    char* ws = (char*)d_ws;
    size_t np = ((size_t)n + 255) & ~(size_t)255;
    int*   cout_ = (int*)ws;   ws += np * 4;
    int*   cin_  = (int*)ws;   ws += np * 4;       // contiguous with cout_ for one memset
    float* oinv  = (float*)ws; ws += np * 4;
    float* iinv  = (float*)ws; ws += np * 4;
    int*   rstart = (int*)ws;  ws += (np + 256) * 4;
    int*   cursor = (int*)ws;  ws += np * 4;
    int2*  edges  = (int2*)ws; ws += (size_t)E * 8;
    size_t fbytes = (size_t)n * DD * sizeof(float);
    float* h0  = (float*)ws;   ws += fbytes;
    float* agg = (float*)ws;   ws += fbytes;       // reused in-place as h1

    hipMemsetAsync(cout_, 0, np * 8, stream);      // zero both histograms

    k_hist<<<(E + 255) / 256, 256, 0, stream>>>(src, dst, cout_, cin_, E);
    k_inv<<<(n + 255) / 256, 256, 0, stream>>>(cout_, cin_, oinv, iinv, n);
    k_scan<<<1, 1024, 0, stream>>>(cin_, rstart, cursor, n);
    k_fill<<<(E + 255) / 256, 256, 0, stream>>>(src, dst, ef, cursor, edges, E);

    int gblocks = (n + 3) / 4;   // one wave per node
    // layer 0: h0 = iinv*oinv * seg_gather(oinv[src]*x[src])
    k_gather<0><<<gblocks, 256, 0, stream>>>(x, edges, rstart, oinv, iinv, h0, n);
    // layer 1: agg = iinv * seg_gather(h0[src])
    k_gather<1><<<gblocks, 256, 0, stream>>>(h0, edges, rstart, oinv, iinv, agg, n);
    // h1 = agg @ W + b (in-place)
    k_gemm<<<(n + 31) / 32, 256, 0, stream>>>(agg, W, b, agg, n);
    // final: out = seg_gather(coef * h1[src])
    k_gather<2><<<gblocks, 256, 0, stream>>>(agg, edges, rstart, oinv, iinv, out, n);
}

// Round 3
// 335.897 us; speedup vs baseline: 2.1045x; 1.2511x over previous
//
#include <hip/hip_runtime.h>

#define DD 64
#define SCAN_CHUNK 2048

// ---------------- degree histogram ----------------
__global__ void k_hist(const int* __restrict__ src, const int* __restrict__ dst,
                       int* __restrict__ cout_, int* __restrict__ cin_, int E) {
    int e = blockIdx.x * blockDim.x + threadIdx.x;
    if (e < E) {
        atomicAdd(&cout_[src[e]], 1);
        atomicAdd(&cin_[dst[e]], 1);
    }
}

__global__ void k_inv(const int* __restrict__ cout_, const int* __restrict__ cin_,
                      float* __restrict__ oinv, float* __restrict__ iinv, int n) {
    int i = blockIdx.x * blockDim.x + threadIdx.x;
    if (i < n) {
        oinv[i] = rsqrtf((float)max(cout_[i], 1));
        iinv[i] = rsqrtf((float)max(cin_[i], 1));
    }
}

// ---------------- 3-phase scan ----------------
// phase 1: per-block (2048-elem chunk) sums
__global__ __launch_bounds__(256) void k_scan1(const int* __restrict__ cnt,
                                               int* __restrict__ partials, int n) {
    int t = threadIdx.x;
    int base = blockIdx.x * SCAN_CHUNK;
    int s = 0;
#pragma unroll
    for (int k = 0; k < 8; ++k) {
        int i = base + t + (k << 8);
        if (i < n) s += cnt[i];
    }
    for (int off = 1; off < 64; off <<= 1) s += __shfl_xor(s, off);
    __shared__ int wsum[4];
    if ((t & 63) == 0) wsum[t >> 6] = s;
    __syncthreads();
    if (t == 0) partials[blockIdx.x] = wsum[0] + wsum[1] + wsum[2] + wsum[3];
}

// phase 2: single small block scans the (<=256) partials; writes total to rstart[n]
__global__ __launch_bounds__(256) void k_scan2(int* __restrict__ partials,
                                               int* __restrict__ rstart, int G, int n) {
    __shared__ int sh[256];
    int t = threadIdx.x;
    int v = (t < G) ? partials[t] : 0;
    sh[t] = v;
    __syncthreads();
    for (int off = 1; off < 256; off <<= 1) {
        int u = (t >= off) ? sh[t - off] : 0;
        __syncthreads();
        sh[t] += u;
        __syncthreads();
    }
    if (t < G) partials[t] = sh[t] - v;   // exclusive block offsets
    if (t == 255) rstart[n] = sh[255];    // total = E
}

// phase 3: per-block local exclusive scan + block offset -> rstart, cursor
__global__ __launch_bounds__(256) void k_scan3(const int* __restrict__ cnt,
                                               const int* __restrict__ partials,
                                               int* __restrict__ rstart,
                                               int* __restrict__ cursor, int n) {
    int t = threadIdx.x;
    int lane = t & 63;
    int w = t >> 6;
    int base = blockIdx.x * SCAN_CHUNK + t * 8;
    int c[8];
    int s8 = 0;
#pragma unroll
    for (int k = 0; k < 8; ++k) {
        int i = base + k;
        c[k] = (i < n) ? cnt[i] : 0;
        s8 += c[k];
    }
    // wave-wide exclusive scan of per-thread sums
    int inc = s8;
    for (int off = 1; off < 64; off <<= 1) {
        int u = __shfl_up(inc, off);
        if (lane >= off) inc += u;
    }
    int excl = inc - s8;
    __shared__ int wtot[4];
    if (lane == 63) wtot[w] = inc;
    __syncthreads();
    int woff = 0;
    for (int i = 0; i < w; ++i) woff += wtot[i];
    int run = partials[blockIdx.x] + woff + excl;
#pragma unroll
    for (int k = 0; k < 8; ++k) {
        int i = base + k;
        if (i < n) { rstart[i] = run; cursor[i] = run; }
        run += c[k];
    }
}

// ---------------- CSR fill: dst-sorted packed records (src | parity<<31) ----------------
__global__ void k_fill(const int* __restrict__ src, const int* __restrict__ dst,
                       const int* __restrict__ ef, int* __restrict__ cursor,
                       int* __restrict__ edges, int E) {
    int e = blockIdx.x * blockDim.x + threadIdx.x;
    if (e < E) {
        int pos = atomicAdd(&cursor[dst[e]], 1);
        edges[pos] = src[e] | ((ef[e] & 1) << 31);
    }
}

// ---------------- gather-sum: y[v] = post(v) * sum_{edges of v} scale(e) * x[src] ----------------
// MODE 0: scale = oinv[src], post = iinv[v]*oinv[v]   (layer0 + fold next layer's input scale)
// MODE 1: scale = 1,         post = iinv[v]           (layer1 aggregation)
// MODE 2: scale = parity ? 1 : 2, post = 1            (final message pass)
template <int MODE>
__global__ __launch_bounds__(256) void k_gather(const float* __restrict__ x,
                                                const int* __restrict__ edges,
                                                const int* __restrict__ row_start,
                                                const float* __restrict__ oinv,
                                                const float* __restrict__ iinv,
                                                float* __restrict__ y, int n) {
    int wave = (blockIdx.x * 256 + threadIdx.x) >> 6;
    if (wave >= n) return;
    int lane = threadIdx.x & 63;
    int sub = lane >> 4;        // 0..3 : edge slot
    int q = lane & 15;          // feature quad: floats [4q, 4q+4)
    int s0 = row_start[wave], s1 = row_start[wave + 1];
    float ax = 0.f, ay = 0.f, az = 0.f, aw = 0.f;
    for (int i = s0 + sub; i < s1; i += 4) {
        int rec = edges[i];
        int s = rec & 0x7fffffff;
        const float4 v = *(const float4*)(x + (size_t)s * DD + q * 4);
        float sc = 1.0f;
        if (MODE == 0) sc = oinv[s];
        if (MODE == 2) sc = (rec < 0) ? 1.0f : 2.0f;
        ax = fmaf(v.x, sc, ax);
        ay = fmaf(v.y, sc, ay);
        az = fmaf(v.z, sc, az);
        aw = fmaf(v.w, sc, aw);
    }
    ax += __shfl_xor(ax, 16); ay += __shfl_xor(ay, 16);
    az += __shfl_xor(az, 16); aw += __shfl_xor(aw, 16);
    ax += __shfl_xor(ax, 32); ay += __shfl_xor(ay, 32);
    az += __shfl_xor(az, 32); aw += __shfl_xor(aw, 32);
    if (sub == 0) {
        float post = 1.0f;
        if (MODE == 0) post = iinv[wave] * oinv[wave];
        if (MODE == 1) post = iinv[wave];
        float4 o = make_float4(ax * post, ay * post, az * post, aw * post);
        *(float4*)(y + (size_t)wave * DD + q * 4) = o;
    }
}

// ---------------- h1 = agg @ W + b  (in-place safe) ----------------
__global__ __launch_bounds__(256) void k_gemm(const float* __restrict__ agg,
                                              const float* __restrict__ W,
                                              const float* __restrict__ b,
                                              float* __restrict__ h1, int n) {
    __shared__ float Wl[64 * 64];
    __shared__ float rows[32][64];
    int tid = threadIdx.x;
    for (int i = tid; i < 64 * 64; i += 256) Wl[i] = W[i];
    int r0 = blockIdx.x * 32;
    for (int i = tid; i < 32 * 64; i += 256) {
        int r = i >> 6;
        int gr = r0 + r;
        rows[r][i & 63] = (gr < n) ? agg[(size_t)gr * 64 + (i & 63)] : 0.0f;
    }
    __syncthreads();
    int col = tid & 63;
    int rg = tid >> 6;
    float bias = b[col];
    for (int rr = 0; rr < 8; ++rr) {
        int r = rg * 8 + rr;
        int gr = r0 + r;
        if (gr >= n) break;
        float acc = bias;
#pragma unroll
        for (int k = 0; k < 64; ++k) acc += rows[r][k] * Wl[k * 64 + col];
        h1[(size_t)gr * 64 + col] = acc;
    }
}

extern "C" void kernel_launch(void* const* d_in, const int* in_sizes, int n_in,
                              void* d_out, int out_size, void* d_ws, size_t ws_size,
                              hipStream_t stream) {
    const float* x   = (const float*)d_in[0];
    const float* W   = (const float*)d_in[1];
    const float* b   = (const float*)d_in[2];
    const int*   src = (const int*)d_in[3];
    const int*   dst = (const int*)d_in[4];
    const int*   ef  = (const int*)d_in[5];
    float* out = (float*)d_out;

    const int n = in_sizes[0] / DD;
    const int E = in_sizes[3];

    char* ws = (char*)d_ws;
    size_t np = ((size_t)n + 255) & ~(size_t)255;
    int*   cout_ = (int*)ws;   ws += np * 4;
    int*   cin_  = (int*)ws;   ws += np * 4;
    float* oinv  = (float*)ws; ws += np * 4;
    float* iinv  = (float*)ws; ws += np * 4;
    int*   rstart = (int*)ws;  ws += (np + 256) * 4;
    int*   cursor = (int*)ws;  ws += np * 4;
    int*   partials = (int*)ws; ws += 256 * 4;
    int*   edges  = (int*)ws;  ws += (size_t)E * 4;
    size_t fbytes = (size_t)n * DD * sizeof(float);
    float* h0  = (float*)ws;   ws += fbytes;
    float* agg = (float*)ws;   ws += fbytes;   // reused in-place as h1

    hipMemsetAsync(cout_, 0, np * 8, stream);  // both histograms

    k_hist<<<(E + 255) / 256, 256, 0, stream>>>(src, dst, cout_, cin_, E);
    k_inv<<<(n + 255) / 256, 256, 0, stream>>>(cout_, cin_, oinv, iinv, n);

    int G = (n + SCAN_CHUNK - 1) / SCAN_CHUNK;   // 25 for n=50000
    k_scan1<<<G, 256, 0, stream>>>(cin_, partials, n);
    k_scan2<<<1, 256, 0, stream>>>(partials, rstart, G, n);
    k_scan3<<<G, 256, 0, stream>>>(cin_, partials, rstart, cursor, n);

    k_fill<<<(E + 255) / 256, 256, 0, stream>>>(src, dst, ef, cursor, edges, E);

    int gblocks = (n + 3) / 4;
    k_gather<0><<<gblocks, 256, 0, stream>>>(x, edges, rstart, oinv, iinv, h0, n);
    k_gather<1><<<gblocks, 256, 0, stream>>>(h0, edges, rstart, oinv, iinv, agg, n);
    k_gemm<<<(n + 31) / 32, 256, 0, stream>>>(agg, W, b, agg, n);
    k_gather<2><<<gblocks, 256, 0, stream>>>(agg, edges, rstart, oinv, iinv, out, n);
}

// Round 4
// 325.485 us; speedup vs baseline: 2.1718x; 1.0320x over previous
//
#include <hip/hip_runtime.h>

#define DD 64
#define SCAN_CHUNK 2048

// ---------------- degree histogram (both) ----------------
__global__ void k_hist(const int* __restrict__ src, const int* __restrict__ dst,
                       int* __restrict__ cout_, int* __restrict__ cin_, int E) {
    int e = blockIdx.x * blockDim.x + threadIdx.x;
    if (e < E) {
        atomicAdd(&cout_[src[e]], 1);
        atomicAdd(&cin_[dst[e]], 1);
    }
}

// ---------------- scan phase 1: per-2048-chunk sums ----------------
__global__ __launch_bounds__(256) void k_scan1(const int* __restrict__ cnt,
                                               int* __restrict__ partials, int n) {
    int t = threadIdx.x;
    int base = blockIdx.x * SCAN_CHUNK;
    int s = 0;
#pragma unroll
    for (int k = 0; k < 8; ++k) {
        int i = base + t + (k << 8);
        if (i < n) s += cnt[i];
    }
    for (int off = 1; off < 64; off <<= 1) s += __shfl_xor(s, off);
    __shared__ int wsum[4];
    if ((t & 63) == 0) wsum[t >> 6] = s;
    __syncthreads();
    if (t == 0) partials[blockIdx.x] = wsum[0] + wsum[1] + wsum[2] + wsum[3];
}

// ---------------- scan phase 2+3 + inv: rstart/cursor/oinv/iinv ----------------
__global__ __launch_bounds__(256) void k_scan23(const int* __restrict__ cnt,      // cin
                                                const int* __restrict__ cout_,
                                                const int* __restrict__ partials,
                                                int* __restrict__ rstart,
                                                int* __restrict__ cursor,
                                                float* __restrict__ oinv,
                                                float* __restrict__ iinv,
                                                int G, int n) {
    int t = threadIdx.x;
    int lane = t & 63;
    int w = t >> 6;
    // every thread: serial exclusive-prefix over <=G partials (tiny, scalar-cached)
    int boff = 0, total = 0;
    for (int g = 0; g < G; ++g) {
        int p = partials[g];
        if (g < (int)blockIdx.x) boff += p;
        total += p;
    }
    if (blockIdx.x == 0 && t == 0) rstart[n] = total;   // = E
    int base = blockIdx.x * SCAN_CHUNK + t * 8;
    int c[8];
    int s8 = 0;
#pragma unroll
    for (int k = 0; k < 8; ++k) {
        int i = base + k;
        c[k] = (i < n) ? cnt[i] : 0;
        s8 += c[k];
    }
    // wave exclusive scan of per-thread sums
    int inc = s8;
    for (int off = 1; off < 64; off <<= 1) {
        int u = __shfl_up(inc, off);
        if (lane >= off) inc += u;
    }
    int excl = inc - s8;
    __shared__ int wtot[4];
    if (lane == 63) wtot[w] = inc;
    __syncthreads();
    int woff = 0;
    for (int i = 0; i < w; ++i) woff += wtot[i];
    int run = boff + woff + excl;
#pragma unroll
    for (int k = 0; k < 8; ++k) {
        int i = base + k;
        if (i < n) {
            rstart[i] = run;
            cursor[i] = run;
            iinv[i] = rsqrtf((float)max(c[k], 1));
            oinv[i] = rsqrtf((float)max(cout_[i], 1));
        }
        run += c[k];
    }
}

// ---------------- CSR fill (blocks [0,fb)) + x pre-scale (blocks [fb,..)) ----------------
__global__ __launch_bounds__(256) void k_fill_scale(const int* __restrict__ src,
                                                    const int* __restrict__ dst,
                                                    const int* __restrict__ ef,
                                                    int* __restrict__ cursor,
                                                    int* __restrict__ edges,
                                                    const float4* __restrict__ x4,
                                                    float4* __restrict__ xs4,
                                                    const float* __restrict__ oinv,
                                                    int E, int fb, int nq) {
    int bid = blockIdx.x;
    if (bid < fb) {
        int e = bid * 256 + threadIdx.x;
        if (e < E) {
            int pos = atomicAdd(&cursor[dst[e]], 1);
            edges[pos] = src[e] | ((ef[e] & 1) << 31);
        }
    } else {
        int i = (bid - fb) * 256 + threadIdx.x;
        if (i < nq) {
            float4 v = x4[i];
            float s = oinv[i >> 4];          // 16 float4 per 64-float row
            xs4[i] = make_float4(v.x * s, v.y * s, v.z * s, v.w * s);
        }
    }
}

// ---------------- gather-sum ----------------
// MODE 0: x pre-scaled by oinv[src]; post = iinv[v]*oinv[v]
// MODE 2: scale = parity ? 1 : 2;    post = 1
template <int MODE>
__global__ __launch_bounds__(256) void k_gather(const float* __restrict__ x,
                                                const int* __restrict__ edges,
                                                const int* __restrict__ row_start,
                                                const float* __restrict__ oinv,
                                                const float* __restrict__ iinv,
                                                float* __restrict__ y, int n) {
    int wave = (blockIdx.x * 256 + threadIdx.x) >> 6;
    if (wave >= n) return;
    int lane = threadIdx.x & 63;
    int sub = lane >> 4;
    int q = lane & 15;
    int s0 = row_start[wave], s1 = row_start[wave + 1];
    float ax = 0.f, ay = 0.f, az = 0.f, aw = 0.f;
    for (int i = s0 + sub; i < s1; i += 4) {
        int rec = edges[i];
        int s = rec & 0x7fffffff;
        const float4 v = *(const float4*)(x + (size_t)s * DD + q * 4);
        float sc = 1.0f;
        if (MODE == 2) sc = (rec < 0) ? 1.0f : 2.0f;
        ax = fmaf(v.x, sc, ax);
        ay = fmaf(v.y, sc, ay);
        az = fmaf(v.z, sc, az);
        aw = fmaf(v.w, sc, aw);
    }
    ax += __shfl_xor(ax, 16); ay += __shfl_xor(ay, 16);
    az += __shfl_xor(az, 16); aw += __shfl_xor(aw, 16);
    ax += __shfl_xor(ax, 32); ay += __shfl_xor(ay, 32);
    az += __shfl_xor(az, 32); aw += __shfl_xor(aw, 32);
    if (sub == 0) {
        float post = 1.0f;
        if (MODE == 0) post = iinv[wave] * oinv[wave];
        float4 o = make_float4(ax * post, ay * post, az * post, aw * post);
        *(float4*)(y + (size_t)wave * DD + q * 4) = o;
    }
}

// ---------------- fused gather + (row*iinv) @ W + b ----------------
__global__ __launch_bounds__(256) void k_gather_gemm(const float* __restrict__ x,
                                                     const int* __restrict__ edges,
                                                     const int* __restrict__ row_start,
                                                     const float* __restrict__ iinv,
                                                     const float* __restrict__ W,
                                                     const float* __restrict__ b,
                                                     float* __restrict__ h1, int n) {
    __shared__ float Wl[64 * 64];      // 16 KB, row-major: Wl[k*64+c]
    __shared__ float bl[64];
    __shared__ float wrow[4][64];      // one row per wave
    int tid = threadIdx.x;
    // stage W (+b) via float4
    const float4* W4 = (const float4*)W;
    float4* Wl4 = (float4*)Wl;
#pragma unroll
    for (int k = 0; k < 4; ++k) Wl4[tid + k * 256] = W4[tid + k * 256];
    if (tid < 64) bl[tid] = b[tid];

    int wave = (blockIdx.x * 256 + tid) >> 6;
    int lane = tid & 63;
    int sub = lane >> 4;
    int q = lane & 15;
    bool valid = wave < n;
    float ax = 0.f, ay = 0.f, az = 0.f, aw = 0.f;
    if (valid) {
        int s0 = row_start[wave], s1 = row_start[wave + 1];
        for (int i = s0 + sub; i < s1; i += 4) {
            int s = edges[i] & 0x7fffffff;
            const float4 v = *(const float4*)(x + (size_t)s * DD + q * 4);
            ax += v.x; ay += v.y; az += v.z; aw += v.w;
        }
    }
    ax += __shfl_xor(ax, 16); ay += __shfl_xor(ay, 16);
    az += __shfl_xor(az, 16); aw += __shfl_xor(aw, 16);
    ax += __shfl_xor(ax, 32); ay += __shfl_xor(ay, 32);
    az += __shfl_xor(az, 32); aw += __shfl_xor(aw, 32);
    __syncthreads();                   // Wl/bl ready; uniform barrier
    int wid = tid >> 6;
    if (valid && sub == 0) {
        float post = iinv[wave];
        *(float4*)&wrow[wid][q * 4] =
            make_float4(ax * post, ay * post, az * post, aw * post);
    }
    __syncthreads();                   // wrow ready (uniform)
    if (valid) {
        float acc = bl[lane];
#pragma unroll
        for (int k = 0; k < 64; ++k) acc = fmaf(wrow[wid][k], Wl[k * 64 + lane], acc);
        h1[(size_t)wave * DD + lane] = acc;
    }
}

extern "C" void kernel_launch(void* const* d_in, const int* in_sizes, int n_in,
                              void* d_out, int out_size, void* d_ws, size_t ws_size,
                              hipStream_t stream) {
    const float* x   = (const float*)d_in[0];
    const float* W   = (const float*)d_in[1];
    const float* b   = (const float*)d_in[2];
    const int*   src = (const int*)d_in[3];
    const int*   dst = (const int*)d_in[4];
    const int*   ef  = (const int*)d_in[5];
    float* out = (float*)d_out;

    const int n = in_sizes[0] / DD;
    const int E = in_sizes[3];

    char* ws = (char*)d_ws;
    size_t np = ((size_t)n + 255) & ~(size_t)255;
    int*   cout_ = (int*)ws;   ws += np * 4;
    int*   cin_  = (int*)ws;   ws += np * 4;
    float* oinv  = (float*)ws; ws += np * 4;
    float* iinv  = (float*)ws; ws += np * 4;
    int*   rstart = (int*)ws;  ws += (np + 256) * 4;
    int*   cursor = (int*)ws;  ws += np * 4;
    int*   partials = (int*)ws; ws += 256 * 4;
    int*   edges  = (int*)ws;  ws += (size_t)E * 4;
    size_t fbytes = (size_t)n * DD * sizeof(float);
    float* xs  = (float*)ws;   ws += fbytes;   // x pre-scaled by oinv
    float* h0  = (float*)ws;   ws += fbytes;
    float* agg = (float*)ws;   ws += fbytes;   // h1 (gemm fused into gather1)

    hipMemsetAsync(cout_, 0, np * 8, stream);  // both histograms

    k_hist<<<(E + 255) / 256, 256, 0, stream>>>(src, dst, cout_, cin_, E);

    int G = (n + SCAN_CHUNK - 1) / SCAN_CHUNK;   // 25
    k_scan1<<<G, 256, 0, stream>>>(cin_, partials, n);
    k_scan23<<<G, 256, 0, stream>>>(cin_, cout_, partials, rstart, cursor,
                                    oinv, iinv, G, n);

    int fb = (E + 255) / 256;
    int nq = n * (DD / 4);                      // float4 count
    int sb = (nq + 255) / 256;
    k_fill_scale<<<fb + sb, 256, 0, stream>>>(src, dst, ef, cursor, edges,
                                              (const float4*)x, (float4*)xs,
                                              oinv, E, fb, nq);

    int gblocks = (n + 3) / 4;
    // layer 0: h0 = iinv*oinv * seg_gather(xs[src])
    k_gather<0><<<gblocks, 256, 0, stream>>>(xs, edges, rstart, oinv, iinv, h0, n);
    // layer 1 + GEMM: h1 = (iinv * seg_gather(h0[src])) @ W + b
    k_gather_gemm<<<gblocks, 256, 0, stream>>>(h0, edges, rstart, iinv, W, b, agg, n);
    // final: out = seg_gather(coef * h1[src])
    k_gather<2><<<gblocks, 256, 0, stream>>>(agg, edges, rstart, oinv, iinv, out, n);
}

// Round 5
// 293.757 us; speedup vs baseline: 2.4064x; 1.1080x over previous
//
#include <hip/hip_runtime.h>

#define DD 64
#define CHUNK_A 4096   // edges per partition block

// ---- kernel 1: per-block bucket counts (dst>>8) + out-degree histogram ----
__global__ __launch_bounds__(256) void k_pre(const int* __restrict__ src,
                                             const int* __restrict__ dst,
                                             int* __restrict__ M,
                                             int* __restrict__ cout_, int E, int PB) {
    int t = threadIdx.x;
    int bid = blockIdx.x;
    if (bid < PB) {
        __shared__ int hist[256];
        hist[t] = 0;
        __syncthreads();
        int base = bid * CHUNK_A;
#pragma unroll
        for (int k = 0; k < CHUNK_A / 256; ++k) {
            int e = base + t + (k << 8);
            if (e < E) atomicAdd(&hist[dst[e] >> 8], 1);
        }
        __syncthreads();
        M[bid * 256 + t] = hist[t];
    } else {
        int e = (bid - PB) * 256 + t;
        if (e < E) atomicAdd(&cout_[src[e]], 1);
    }
}

// ---- kernel 2: block 0 scans bucket matrix -> global offsets; tail blocks: oinv ----
__global__ __launch_bounds__(256) void k_binscan(int* __restrict__ M,
                                                 int* __restrict__ binBase,
                                                 int* __restrict__ rstart,
                                                 const int* __restrict__ cout_,
                                                 float* __restrict__ oinv,
                                                 int PB, int n, int E) {
    int t = threadIdx.x;
    if (blockIdx.x == 0) {
        int tot = 0;
        for (int p = 0; p < PB; ++p) tot += M[p * 256 + t];   // coalesced column sums
        int lane = t & 63, w = t >> 6;
        int inc = tot;
        for (int o = 1; o < 64; o <<= 1) {
            int u = __shfl_up(inc, o);
            if (lane >= o) inc += u;
        }
        __shared__ int wtot[4];
        if (lane == 63) wtot[w] = inc;
        __syncthreads();
        int woff = 0;
        for (int i = 0; i < w; ++i) woff += wtot[i];
        int base = woff + inc - tot;                          // exclusive bin base
        binBase[t] = base;
        if (t == 255) { binBase[256] = base + tot; rstart[n] = E; }
        int run = base;
#pragma unroll 4
        for (int p = 0; p < PB; ++p) {
            int v = M[p * 256 + t];
            M[p * 256 + t] = run;                             // per-(block,bin) start
            run += v;
        }
    } else {
        int i = (blockIdx.x - 1) * 256 + t;
        if (i < n) oinv[i] = rsqrtf((float)max(cout_[i], 1));
    }
}

// ---- kernel 3: scatter edges into coarse buckets (LDS cursors, no global atomics) ----
__global__ __launch_bounds__(256) void k_scatterA(const int* __restrict__ src,
                                                  const int* __restrict__ dst,
                                                  const int* __restrict__ ef,
                                                  const int* __restrict__ M,
                                                  int* __restrict__ bucketA, int E) {
    __shared__ int cur[256];
    int t = threadIdx.x;
    int p = blockIdx.x;
    cur[t] = M[p * 256 + t];
    __syncthreads();
    int base = p * CHUNK_A;
#pragma unroll
    for (int k = 0; k < CHUNK_A / 256; ++k) {
        int e = base + t + (k << 8);
        if (e < E) {
            int d = dst[e];
            int pos = atomicAdd(&cur[d >> 8], 1);
            // pack: src (17b) | parity<<17 | dst&255 << 18
            bucketA[pos] = src[e] | ((ef[e] & 1) << 17) | ((d & 255) << 18);
        }
    }
}

// ---- kernel 4: per-bucket group by dst&255; emit final edges + rstart + iinv ----
__global__ __launch_bounds__(256) void k_bucket(const int* __restrict__ bucketA,
                                                const int* __restrict__ binBase,
                                                int* __restrict__ rstart,
                                                float* __restrict__ iinv,
                                                int* __restrict__ edges, int n) {
    __shared__ int cnt[256];
    __shared__ int off[256];
    __shared__ int wtot[4];
    int t = threadIdx.x;
    int b = blockIdx.x;
    int s0 = binBase[b], s1 = binBase[b + 1];
    cnt[t] = 0;
    __syncthreads();
    for (int i = s0 + t; i < s1; i += 256)
        atomicAdd(&cnt[(bucketA[i] >> 18) & 255], 1);
    __syncthreads();
    int c = cnt[t];
    int lane = t & 63, w = t >> 6;
    int inc = c;
    for (int o = 1; o < 64; o <<= 1) {
        int u = __shfl_up(inc, o);
        if (lane >= o) inc += u;
    }
    if (lane == 63) wtot[w] = inc;
    __syncthreads();
    int woff = 0;
    for (int i = 0; i < w; ++i) woff += wtot[i];
    int excl = woff + inc - c;
    int v = b * 256 + t;
    if (v < n) {
        rstart[v] = s0 + excl;
        iinv[v] = rsqrtf((float)max(c, 1));
    }
    off[t] = excl;                       // becomes local cursor
    __syncthreads();
    for (int i = s0 + t; i < s1; i += 256) {
        int r = bucketA[i];
        int cc = (r >> 18) & 255;
        int pos = atomicAdd(&off[cc], 1);
        edges[s0 + pos] = (r & 0x1FFFF) | (int)(((unsigned)((r >> 17) & 1)) << 31);
    }
}

// ---- gather-sum: y[v] = post(v) * sum scale(e) * x[src] ----
// MODE 0: scale = oinv[src], post = iinv[v]*oinv[v]
// MODE 2: scale = parity ? 1 : 2, post = 1
template <int MODE>
__global__ __launch_bounds__(256) void k_gather(const float* __restrict__ x,
                                                const int* __restrict__ edges,
                                                const int* __restrict__ row_start,
                                                const float* __restrict__ oinv,
                                                const float* __restrict__ iinv,
                                                float* __restrict__ y, int n) {
    int wave = (blockIdx.x * 256 + threadIdx.x) >> 6;
    if (wave >= n) return;
    int lane = threadIdx.x & 63;
    int sub = lane >> 4;
    int q = lane & 15;
    int s0 = row_start[wave], s1 = row_start[wave + 1];
    float ax = 0.f, ay = 0.f, az = 0.f, aw = 0.f;
    for (int i = s0 + sub; i < s1; i += 4) {
        int rec = edges[i];
        int s = rec & 0x7fffffff;
        const float4 v = *(const float4*)(x + (size_t)s * DD + q * 4);
        float sc = 1.0f;
        if (MODE == 0) sc = oinv[s];
        if (MODE == 2) sc = (rec < 0) ? 1.0f : 2.0f;
        ax = fmaf(v.x, sc, ax);
        ay = fmaf(v.y, sc, ay);
        az = fmaf(v.z, sc, az);
        aw = fmaf(v.w, sc, aw);
    }
    ax += __shfl_xor(ax, 16); ay += __shfl_xor(ay, 16);
    az += __shfl_xor(az, 16); aw += __shfl_xor(aw, 16);
    ax += __shfl_xor(ax, 32); ay += __shfl_xor(ay, 32);
    az += __shfl_xor(az, 32); aw += __shfl_xor(aw, 32);
    if (sub == 0) {
        float post = 1.0f;
        if (MODE == 0) post = iinv[wave] * oinv[wave];
        float4 o = make_float4(ax * post, ay * post, az * post, aw * post);
        *(float4*)(y + (size_t)wave * DD + q * 4) = o;
    }
}

// ---- fused gather + (row*iinv) @ W + b ----
__global__ __launch_bounds__(256) void k_gather_gemm(const float* __restrict__ x,
                                                     const int* __restrict__ edges,
                                                     const int* __restrict__ row_start,
                                                     const float* __restrict__ iinv,
                                                     const float* __restrict__ W,
                                                     const float* __restrict__ b,
                                                     float* __restrict__ h1, int n) {
    __shared__ float Wl[64 * 64];
    __shared__ float bl[64];
    __shared__ float wrow[4][64];
    int tid = threadIdx.x;
    const float4* W4 = (const float4*)W;
    float4* Wl4 = (float4*)Wl;
#pragma unroll
    for (int k = 0; k < 4; ++k) Wl4[tid + k * 256] = W4[tid + k * 256];
    if (tid < 64) bl[tid] = b[tid];

    int wave = (blockIdx.x * 256 + tid) >> 6;
    int lane = tid & 63;
    int sub = lane >> 4;
    int q = lane & 15;
    bool valid = wave < n;
    float ax = 0.f, ay = 0.f, az = 0.f, aw = 0.f;
    if (valid) {
        int s0 = row_start[wave], s1 = row_start[wave + 1];
        for (int i = s0 + sub; i < s1; i += 4) {
            int s = edges[i] & 0x7fffffff;
            const float4 v = *(const float4*)(x + (size_t)s * DD + q * 4);
            ax += v.x; ay += v.y; az += v.z; aw += v.w;
        }
    }
    ax += __shfl_xor(ax, 16); ay += __shfl_xor(ay, 16);
    az += __shfl_xor(az, 16); aw += __shfl_xor(aw, 16);
    ax += __shfl_xor(ax, 32); ay += __shfl_xor(ay, 32);
    az += __shfl_xor(az, 32); aw += __shfl_xor(aw, 32);
    __syncthreads();
    int wid = tid >> 6;
    if (valid && sub == 0) {
        float post = iinv[wave];
        *(float4*)&wrow[wid][q * 4] =
            make_float4(ax * post, ay * post, az * post, aw * post);
    }
    __syncthreads();
    if (valid) {
        float acc = bl[lane];
#pragma unroll
        for (int k = 0; k < 64; ++k) acc = fmaf(wrow[wid][k], Wl[k * 64 + lane], acc);
        h1[(size_t)wave * DD + lane] = acc;
    }
}

extern "C" void kernel_launch(void* const* d_in, const int* in_sizes, int n_in,
                              void* d_out, int out_size, void* d_ws, size_t ws_size,
                              hipStream_t stream) {
    const float* x   = (const float*)d_in[0];
    const float* W   = (const float*)d_in[1];
    const float* b   = (const float*)d_in[2];
    const int*   src = (const int*)d_in[3];
    const int*   dst = (const int*)d_in[4];
    const int*   ef  = (const int*)d_in[5];
    float* out = (float*)d_out;

    const int n = in_sizes[0] / DD;
    const int E = in_sizes[3];

    const int PB = (E + CHUNK_A - 1) / CHUNK_A;      // 196 partition blocks
    const int NB = (n + 255) >> 8;                   // 196 coarse buckets
    const int HB = (E + 255) / 256;                  // hist blocks
    const int SB = (n + 255) / 256;                  // oinv blocks

    char* ws = (char*)d_ws;
    size_t np = ((size_t)n + 255) & ~(size_t)255;
    int*   cout_  = (int*)ws;   ws += np * 4;
    float* oinv   = (float*)ws; ws += np * 4;
    float* iinv   = (float*)ws; ws += np * 4;
    int*   rstart = (int*)ws;   ws += (np + 256) * 4;
    int*   binBase= (int*)ws;   ws += 260 * 4;
    int*   M      = (int*)ws;   ws += (size_t)PB * 256 * 4;
    int*   bucketA= (int*)ws;   ws += (size_t)E * 4;
    int*   edges  = (int*)ws;   ws += (size_t)E * 4;
    size_t fbytes = (size_t)n * DD * sizeof(float);
    float* h0  = (float*)ws;    ws += fbytes;
    float* agg = (float*)ws;    ws += fbytes;

    hipMemsetAsync(cout_, 0, np * 4, stream);

    k_pre<<<PB + HB, 256, 0, stream>>>(src, dst, M, cout_, E, PB);
    k_binscan<<<1 + SB, 256, 0, stream>>>(M, binBase, rstart, cout_, oinv, PB, n, E);
    k_scatterA<<<PB, 256, 0, stream>>>(src, dst, ef, M, bucketA, E);
    k_bucket<<<NB, 256, 0, stream>>>(bucketA, binBase, rstart, iinv, edges, n);

    int gblocks = (n + 3) / 4;
    k_gather<0><<<gblocks, 256, 0, stream>>>(x, edges, rstart, oinv, iinv, h0, n);
    k_gather_gemm<<<gblocks, 256, 0, stream>>>(h0, edges, rstart, iinv, W, b, agg, n);
    k_gather<2><<<gblocks, 256, 0, stream>>>(agg, edges, rstart, oinv, iinv, out, n);
}

// Round 11
// 256.283 us; speedup vs baseline: 2.7583x; 1.1462x over previous
//
#include <hip/hip_runtime.h>

#define DD 64
#define CHUNK_A 4096            // edges per partition block
#define SRC_MASK 0x1FFFF        // 17 bits: N = 50000 < 131072

// ---- kernel 1: dual per-block bucket counts (dst>>8 and src>>8) ----
__global__ __launch_bounds__(256) void k_pre(const int* __restrict__ src,
                                             const int* __restrict__ dst,
                                             int* __restrict__ M,
                                             int* __restrict__ Msrc, int E) {
    __shared__ int hd[256], hs[256];
    int t = threadIdx.x;
    int bid = blockIdx.x;
    hd[t] = 0; hs[t] = 0;
    __syncthreads();
    int base = bid * CHUNK_A;
#pragma unroll
    for (int k = 0; k < CHUNK_A / 256; ++k) {
        int e = base + t + (k << 8);
        if (e < E) {
            atomicAdd(&hd[dst[e] >> 8], 1);
            atomicAdd(&hs[src[e] >> 8], 1);
        }
    }
    __syncthreads();
    M[bid * 256 + t] = hd[t];
    Msrc[bid * 256 + t] = hs[t];
}

// ---- kernel 2: two blocks, each scans one bucket matrix -> bases + running starts ----
__global__ __launch_bounds__(256) void k_binscan(int* __restrict__ M,
                                                 int* __restrict__ Msrc,
                                                 int* __restrict__ binBase,
                                                 int* __restrict__ binBaseS,
                                                 int* __restrict__ rstart,
                                                 int PB, int n, int E) {
    int t = threadIdx.x;
    int* Mx = (blockIdx.x == 0) ? M : Msrc;
    int* bb = (blockIdx.x == 0) ? binBase : binBaseS;
    int tot = 0;
    for (int p = 0; p < PB; ++p) tot += Mx[p * 256 + t];   // coalesced column sums
    int lane = t & 63, w = t >> 6;
    int inc = tot;
    for (int o = 1; o < 64; o <<= 1) {
        int u = __shfl_up(inc, o);
        if (lane >= o) inc += u;
    }
    __shared__ int wtot[4];
    if (lane == 63) wtot[w] = inc;
    __syncthreads();
    int woff = 0;
    for (int i = 0; i < w; ++i) woff += wtot[i];
    int base = woff + inc - tot;                           // exclusive bin base
    bb[t] = base;
    if (t == 255) bb[256] = base + tot;                    // = E
    if (blockIdx.x == 0 && t == 0) rstart[n] = E;
    int run = base;
#pragma unroll 4
    for (int p = 0; p < PB; ++p) {
        int v = Mx[p * 256 + t];
        Mx[p * 256 + t] = run;                             // per-(block,bin) start
        run += v;
    }
}

// ---- kernel 3: dual scatter, LDS cursors, no global atomics ----
__global__ __launch_bounds__(256) void k_scatterA(const int* __restrict__ src,
                                                  const int* __restrict__ dst,
                                                  const int* __restrict__ ef,
                                                  const int* __restrict__ M,
                                                  const int* __restrict__ Msrc,
                                                  int* __restrict__ bucketA,
                                                  unsigned char* __restrict__ bucketS,
                                                  int E) {
    __shared__ int curD[256], curS[256];
    int t = threadIdx.x;
    int p = blockIdx.x;
    curD[t] = M[p * 256 + t];
    curS[t] = Msrc[p * 256 + t];
    __syncthreads();
    int base = p * CHUNK_A;
#pragma unroll
    for (int k = 0; k < CHUNK_A / 256; ++k) {
        int e = base + t + (k << 8);
        if (e < E) {
            int s = src[e], d = dst[e];
            int posD = atomicAdd(&curD[d >> 8], 1);
            bucketA[posD] = s | ((ef[e] & 1) << 17) | ((d & 255) << 18);
            int posS = atomicAdd(&curS[s >> 8], 1);
            bucketS[posS] = (unsigned char)(s & 255);
        }
    }
}

// ---- kernel 4: blocks [0,NB): dst grouping -> edges+rstart+iinv; [NB,2NB): src counts -> oinv ----
__global__ __launch_bounds__(256) void k_bucket(const int* __restrict__ bucketA,
                                                const unsigned char* __restrict__ bucketS,
                                                const int* __restrict__ binBase,
                                                const int* __restrict__ binBaseS,
                                                int* __restrict__ rstart,
                                                float* __restrict__ iinv,
                                                float* __restrict__ oinv,
                                                int* __restrict__ edges, int n, int NB) {
    __shared__ int cnt[256];
    __shared__ int off[256];
    __shared__ int wtot[4];
    int t = threadIdx.x;
    int b = blockIdx.x;
    if (b < NB) {
        int s0 = binBase[b], s1 = binBase[b + 1];
        cnt[t] = 0;
        __syncthreads();
        for (int i = s0 + t; i < s1; i += 256)
            atomicAdd(&cnt[(bucketA[i] >> 18) & 255], 1);
        __syncthreads();
        int c = cnt[t];
        int lane = t & 63, w = t >> 6;
        int inc = c;
        for (int o = 1; o < 64; o <<= 1) {
            int u = __shfl_up(inc, o);
            if (lane >= o) inc += u;
        }
        if (lane == 63) wtot[w] = inc;
        __syncthreads();
        int woff = 0;
        for (int i = 0; i < w; ++i) woff += wtot[i];
        int excl = woff + inc - c;
        int v = b * 256 + t;
        if (v < n) {
            rstart[v] = s0 + excl;
            iinv[v] = rsqrtf((float)max(c, 1));
        }
        off[t] = excl;
        __syncthreads();
        for (int i = s0 + t; i < s1; i += 256) {
            int r = bucketA[i];
            int cc = (r >> 18) & 255;
            int pos = atomicAdd(&off[cc], 1);
            edges[s0 + pos] = (r & SRC_MASK) | (int)(((unsigned)((r >> 17) & 1)) << 31);
        }
    } else {
        int bs = b - NB;
        int s0 = binBaseS[bs], s1 = binBaseS[bs + 1];
        cnt[t] = 0;
        __syncthreads();
        for (int i = s0 + t; i < s1; i += 256)
            atomicAdd(&cnt[(int)bucketS[i]], 1);
        __syncthreads();
        int v = bs * 256 + t;
        if (v < n) oinv[v] = rsqrtf((float)max(cnt[t], 1));
    }
}

// ---- gather-sum, pair-unrolled (8 row-loads in flight per wave) ----
// MODE 0: scale = oinv[src], post = iinv[v]*oinv[v]
// MODE 2: scale = parity ? 1 : 2, post = 1
template <int MODE>
__global__ __launch_bounds__(256) void k_gather(const float* __restrict__ x,
                                                const int* __restrict__ edges,
                                                const int* __restrict__ row_start,
                                                const float* __restrict__ oinv,
                                                const float* __restrict__ iinv,
                                                float* __restrict__ y, int n) {
    int wave = (blockIdx.x * 256 + threadIdx.x) >> 6;
    if (wave >= n) return;
    int lane = threadIdx.x & 63;
    int sub = lane >> 4;
    int q = lane & 15;
    int s0 = row_start[wave], s1 = row_start[wave + 1];
    float ax = 0.f, ay = 0.f, az = 0.f, aw = 0.f;
    int i = s0 + sub;
    for (; i + 4 < s1; i += 8) {
        int r0 = edges[i], r1 = edges[i + 4];
        int sa = r0 & SRC_MASK, sb = r1 & SRC_MASK;
        const float4 v0 = *(const float4*)(x + (size_t)sa * DD + q * 4);
        const float4 v1 = *(const float4*)(x + (size_t)sb * DD + q * 4);
        float c0 = 1.0f, c1 = 1.0f;
        if (MODE == 0) { c0 = oinv[sa]; c1 = oinv[sb]; }
        if (MODE == 2) { c0 = (r0 < 0) ? 1.0f : 2.0f; c1 = (r1 < 0) ? 1.0f : 2.0f; }
        ax = fmaf(v0.x, c0, ax); ay = fmaf(v0.y, c0, ay);
        az = fmaf(v0.z, c0, az); aw = fmaf(v0.w, c0, aw);
        ax = fmaf(v1.x, c1, ax); ay = fmaf(v1.y, c1, ay);
        az = fmaf(v1.z, c1, az); aw = fmaf(v1.w, c1, aw);
    }
    if (i < s1) {
        int r0 = edges[i];
        int sa = r0 & SRC_MASK;
        const float4 v0 = *(const float4*)(x + (size_t)sa * DD + q * 4);
        float c0 = 1.0f;
        if (MODE == 0) c0 = oinv[sa];
        if (MODE == 2) c0 = (r0 < 0) ? 1.0f : 2.0f;
        ax = fmaf(v0.x, c0, ax); ay = fmaf(v0.y, c0, ay);
        az = fmaf(v0.z, c0, az); aw = fmaf(v0.w, c0, aw);
    }
    ax += __shfl_xor(ax, 16); ay += __shfl_xor(ay, 16);
    az += __shfl_xor(az, 16); aw += __shfl_xor(aw, 16);
    ax += __shfl_xor(ax, 32); ay += __shfl_xor(ay, 32);
    az += __shfl_xor(az, 32); aw += __shfl_xor(aw, 32);
    if (sub == 0) {
        float post = 1.0f;
        if (MODE == 0) post = iinv[wave] * oinv[wave];
        float4 o = make_float4(ax * post, ay * post, az * post, aw * post);
        *(float4*)(y + (size_t)wave * DD + q * 4) = o;
    }
}

// ---- fused gather + (row*iinv) @ W + b, pair-unrolled ----
__global__ __launch_bounds__(256) void k_gather_gemm(const float* __restrict__ x,
                                                     const int* __restrict__ edges,
                                                     const int* __restrict__ row_start,
                                                     const float* __restrict__ iinv,
                                                     const float* __restrict__ W,
                                                     const float* __restrict__ b,
                                                     float* __restrict__ h1, int n) {
    __shared__ float Wl[64 * 64];
    __shared__ float bl[64];
    __shared__ float wrow[4][64];
    int tid = threadIdx.x;
    const float4* W4 = (const float4*)W;
    float4* Wl4 = (float4*)Wl;
#pragma unroll
    for (int k = 0; k < 4; ++k) Wl4[tid + k * 256] = W4[tid + k * 256];
    if (tid < 64) bl[tid] = b[tid];

    int wave = (blockIdx.x * 256 + tid) >> 6;
    int lane = tid & 63;
    int sub = lane >> 4;
    int q = lane & 15;
    bool valid = wave < n;
    float ax = 0.f, ay = 0.f, az = 0.f, aw = 0.f;
    if (valid) {
        int s0 = row_start[wave], s1 = row_start[wave + 1];
        int i = s0 + sub;
        for (; i + 4 < s1; i += 8) {
            int sa = edges[i] & SRC_MASK, sb = edges[i + 4] & SRC_MASK;
            const float4 v0 = *(const float4*)(x + (size_t)sa * DD + q * 4);
            const float4 v1 = *(const float4*)(x + (size_t)sb * DD + q * 4);
            ax += v0.x; ay += v0.y; az += v0.z; aw += v0.w;
            ax += v1.x; ay += v1.y; az += v1.z; aw += v1.w;
        }
        if (i < s1) {
            int sa = edges[i] & SRC_MASK;
            const float4 v0 = *(const float4*)(x + (size_t)sa * DD + q * 4);
            ax += v0.x; ay += v0.y; az += v0.z; aw += v0.w;
        }
    }
    ax += __shfl_xor(ax, 16); ay += __shfl_xor(ay, 16);
    az += __shfl_xor(az, 16); aw += __shfl_xor(aw, 16);
    ax += __shfl_xor(ax, 32); ay += __shfl_xor(ay, 32);
    az += __shfl_xor(az, 32); aw += __shfl_xor(aw, 32);
    __syncthreads();
    int wid = tid >> 6;
    if (valid && sub == 0) {
        float post = iinv[wave];
        *(float4*)&wrow[wid][q * 4] =
            make_float4(ax * post, ay * post, az * post, aw * post);
    }
    __syncthreads();
    if (valid) {
        float acc = bl[lane];
#pragma unroll
        for (int k = 0; k < 64; ++k) acc = fmaf(wrow[wid][k], Wl[k * 64 + lane], acc);
        h1[(size_t)wave * DD + lane] = acc;
    }
}

extern "C" void kernel_launch(void* const* d_in, const int* in_sizes, int n_in,
                              void* d_out, int out_size, void* d_ws, size_t ws_size,
                              hipStream_t stream) {
    const float* x   = (const float*)d_in[0];
    const float* W   = (const float*)d_in[1];
    const float* b   = (const float*)d_in[2];
    const int*   src = (const int*)d_in[3];
    const int*   dst = (const int*)d_in[4];
    const int*   ef  = (const int*)d_in[5];
    float* out = (float*)d_out;

    const int n = in_sizes[0] / DD;
    const int E = in_sizes[3];

    const int PB = (E + CHUNK_A - 1) / CHUNK_A;      // 196 partition blocks
    const int NB = (n + 255) >> 8;                   // 196 coarse buckets

    char* ws = (char*)d_ws;
    size_t np = ((size_t)n + 255) & ~(size_t)255;
    float* oinv    = (float*)ws; ws += np * 4;
    float* iinv    = (float*)ws; ws += np * 4;
    int*   rstart  = (int*)ws;   ws += (np + 256) * 4;
    int*   binBase = (int*)ws;   ws += 260 * 4;
    int*   binBaseS= (int*)ws;   ws += 260 * 4;
    int*   M       = (int*)ws;   ws += (size_t)PB * 256 * 4;
    int*   Msrc    = (int*)ws;   ws += (size_t)PB * 256 * 4;
    int*   bucketA = (int*)ws;   ws += (size_t)E * 4;
    unsigned char* bucketS = (unsigned char*)ws; ws += ((size_t)E + 255) & ~(size_t)255;
    int*   edges   = (int*)ws;   ws += (size_t)E * 4;
    size_t fbytes = (size_t)n * DD * sizeof(float);
    float* h0  = (float*)ws;    ws += fbytes;
    float* agg = (float*)ws;    ws += fbytes;

    k_pre<<<PB, 256, 0, stream>>>(src, dst, M, Msrc, E);
    k_binscan<<<2, 256, 0, stream>>>(M, Msrc, binBase, binBaseS, rstart, PB, n, E);
    k_scatterA<<<PB, 256, 0, stream>>>(src, dst, ef, M, Msrc, bucketA, bucketS, E);
    k_bucket<<<2 * NB, 256, 0, stream>>>(bucketA, bucketS, binBase, binBaseS,
                                         rstart, iinv, oinv, edges, n, NB);

    int gblocks = (n + 3) / 4;
    k_gather<0><<<gblocks, 256, 0, stream>>>(x, edges, rstart, oinv, iinv, h0, n);
    k_gather_gemm<<<gblocks, 256, 0, stream>>>(h0, edges, rstart, iinv, W, b, agg, n);
    k_gather<2><<<gblocks, 256, 0, stream>>>(agg, edges, rstart, oinv, iinv, out, n);
}